// Round 1
// 614.584 us; speedup vs baseline: 1.0037x; 1.0037x over previous
//
#include <hip/hip_runtime.h>

// GNN TARnet: h = x*emb -> 2x graph conv -> two prob heads.
// R5: k_head hot loop rewritten with inline-asm global_load_dwordx4 in an
//     8-deep rolling register pipeline + counted s_waitcnt vmcnt(N) (never 0
//     in steady state) + sched_barrier(0) fences. Theory: compiler collapsed
//     the R3/R4 source-level 4-deep prefetch (VGPR_Count=44 < the 48+ needed
//     for it to be live), leaving ~1 load in flight/wave -> 2.8 TB/s delivered
//     vs 6.3 ceiling. Everything else identical to R4.

constexpr int B = 8, N = 5000, E = 160000, D = 64, H = 128;
constexpr int BN = B * N;           // 40000
constexpr int ND = N * D;           // 320000
constexpr long BND = (long)BN * D;  // 2,560,000
constexpr int KC = 320;             // k-chunk per head block
constexpr int NIT = KC / 8;         // 40 k-iters per thread
constexpr int XB = ND / KC;         // 1000 x-blocks per head

using f32x4 = __attribute__((ext_vector_type(4))) float;

__device__ __forceinline__ float elu_f(float x) {
    return x > 0.0f ? x : __expf(x) - 1.0f;
}

// ---------------- CSR build (edges grouped by child) ----------------
__global__ __launch_bounds__(256) void k_count(const int* __restrict__ edges,
                                               int* __restrict__ cnt) {
    int i = blockIdx.x * 256 + threadIdx.x;
    if (i < E) atomicAdd(&cnt[edges[2 * i + 1]], 1);
}

__global__ __launch_bounds__(256) void k_scan(const int* __restrict__ cnt,
                                              int* __restrict__ offs) {
    __shared__ int part[256];
    int t = threadIdx.x;
    const int CH = 20;
    int base = t * CH;
    int s = 0;
    for (int i = 0; i < CH; ++i) { int idx = base + i; if (idx < N) s += cnt[idx]; }
    part[t] = s;
    __syncthreads();
    for (int off = 1; off < 256; off <<= 1) {
        int add = (t >= off) ? part[t - off] : 0;
        __syncthreads();
        part[t] += add;
        __syncthreads();
    }
    int run = part[t] - s;
    for (int i = 0; i < CH; ++i) {
        int idx = base + i;
        if (idx < N) { offs[idx] = run; run += cnt[idx]; }
    }
    if (t == 255) offs[N] = run;
}

__global__ __launch_bounds__(256) void k_fill(const int* __restrict__ edges,
                                              const int* __restrict__ offs,
                                              int* __restrict__ cursor,
                                              int* __restrict__ elist) {
    int i = blockIdx.x * 256 + threadIdx.x;
    if (i < E) {
        int child = edges[2 * i + 1];
        int pos = offs[child] + atomicAdd(&cursor[child], 1);
        elist[pos] = edges[2 * i];
    }
}

// ---------------- prepare: M = elu(elu(h @ W1) @ W2) ----------------
__global__ __launch_bounds__(512) void k_prepare(const float* __restrict__ xsrc,
                                                 const float* __restrict__ emb,
                                                 const float* __restrict__ hin,
                                                 const float* __restrict__ W1,
                                                 const float* __restrict__ W2,
                                                 float* __restrict__ M,
                                                 float* __restrict__ hwt) {
    __shared__ float sW1[64 * 64];      // 16 KB
    __shared__ float sP[128 * 65];      // 33.3 KB
    int t = threadIdx.x;
    int r0 = blockIdx.x * 128;
    for (int i = t; i < 4096; i += 512) sW1[i] = W1[i];
    if (xsrc) {
        for (int i = t; i < 128 * 64; i += 512) {
            int r = i >> 6, c = i & 63;
            int row = r0 + r;
            float v = 0.0f;
            if (row < BN) {
                int n = row % N;
                v = xsrc[row] * emb[n * 64 + c];
                hwt[(long)row * 64 + c] = v;
            }
            sP[r * 65 + c] = v;
        }
    } else {
        for (int i = t; i < 128 * 64; i += 512) {
            int r = i >> 6, c = i & 63;
            int row = r0 + r;
            sP[r * 65 + c] = (row < BN) ? hin[(long)row * 64 + c] : 0.0f;
        }
    }
    __syncthreads();

    int cg = t & 15, rg = t >> 4;
    float acc[4][4] = {};
    #pragma unroll 4
    for (int k = 0; k < 64; ++k) {
        float a[4];
        #pragma unroll
        for (int i = 0; i < 4; ++i) a[i] = sP[(rg * 4 + i) * 65 + k];
        float4 bb = *reinterpret_cast<const float4*>(&sW1[k * 64 + cg * 4]);
        #pragma unroll
        for (int i = 0; i < 4; ++i) {
            acc[i][0] += a[i] * bb.x; acc[i][1] += a[i] * bb.y;
            acc[i][2] += a[i] * bb.z; acc[i][3] += a[i] * bb.w;
        }
    }
    __syncthreads();
    #pragma unroll
    for (int i = 0; i < 4; ++i)
        #pragma unroll
        for (int j = 0; j < 4; ++j)
            sP[(rg * 4 + i) * 65 + cg * 4 + j] = elu_f(acc[i][j]);
    __syncthreads();

    float acc2[4][4] = {};
    #pragma unroll 4
    for (int k = 0; k < 64; ++k) {
        float a[4];
        #pragma unroll
        for (int i = 0; i < 4; ++i) a[i] = sP[(rg * 4 + i) * 65 + k];
        float4 bb = *reinterpret_cast<const float4*>(&W2[k * 64 + cg * 4]);
        #pragma unroll
        for (int i = 0; i < 4; ++i) {
            acc2[i][0] += a[i] * bb.x; acc2[i][1] += a[i] * bb.y;
            acc2[i][2] += a[i] * bb.z; acc2[i][3] += a[i] * bb.w;
        }
    }
    #pragma unroll
    for (int i = 0; i < 4; ++i) {
        int row = r0 + rg * 4 + i;
        if (row < BN) {
            float4 o = make_float4(elu_f(acc2[i][0]), elu_f(acc2[i][1]),
                                   elu_f(acc2[i][2]), elu_f(acc2[i][3]));
            *reinterpret_cast<float4*>(&M[(long)row * 64 + cg * 4]) = o;
        }
    }
}

// ---------------- agg[b,n,:] = sum_{e: child==n} M[b, parent_e, :] ----------------
__global__ __launch_bounds__(256) void k_aggregate(const float* __restrict__ M,
                                                   const int* __restrict__ offs,
                                                   const int* __restrict__ elist,
                                                   float* __restrict__ agg) {
    int t = threadIdx.x;
    int lane = t & 63, wv = t >> 6;
    int bn = blockIdx.x * 4 + wv;
    int b = bn / N;
    int n = bn - b * N;
    int e0 = offs[n], e1 = offs[n + 1];
    const float* Mb = M + (long)b * ND;
    int h4 = lane & 15, le = lane >> 4;
    float4 acc = make_float4(0.f, 0.f, 0.f, 0.f);
    for (int e = e0 + le; e < e1; e += 4) {
        int p = elist[e];
        float4 v = *reinterpret_cast<const float4*>(&Mb[(long)p * 64 + h4 * 4]);
        acc.x += v.x; acc.y += v.y; acc.z += v.z; acc.w += v.w;
    }
    #pragma unroll
    for (int m = 16; m <= 32; m <<= 1) {
        acc.x += __shfl_xor(acc.x, m);
        acc.y += __shfl_xor(acc.y, m);
        acc.z += __shfl_xor(acc.z, m);
        acc.w += __shfl_xor(acc.w, m);
    }
    if (le == 0)
        *reinterpret_cast<float4*>(&agg[(long)bn * 64 + h4 * 4]) = acc;
}

// ---------------- fused update: hout = (elu([h,agg]@W1 + b1)) @ W2 + b2 ----------------
__global__ __launch_bounds__(512) void k_update(const float* __restrict__ h,
                                                const float* __restrict__ agg,
                                                const float* __restrict__ W1,   // [128][64]
                                                const float* __restrict__ b1,
                                                const float* __restrict__ W2,   // [64][64]
                                                const float* __restrict__ b2,
                                                float* __restrict__ hout) {
    __shared__ float sW1[128 * 64];     // 32 KB
    __shared__ float sP[64 * 129];      // 33 KB
    int t = threadIdx.x;
    long r0 = (long)blockIdx.x * 64;
    for (int i = t; i < 128 * 64; i += 512) sW1[i] = W1[i];
    for (int i = t; i < 64 * 128; i += 512) {
        int r = i >> 7, k = i & 127;
        long row = r0 + r;
        float v = (k < 64) ? h[row * 64 + k] : agg[row * 64 + (k - 64)];
        sP[r * 129 + k] = v;
    }
    __syncthreads();

    int cg = t & 15, rg = t >> 4;
    float acc[2][4] = {};
    #pragma unroll 4
    for (int k = 0; k < 128; ++k) {
        float a0 = sP[(rg * 2 + 0) * 129 + k];
        float a1 = sP[(rg * 2 + 1) * 129 + k];
        float4 bb = *reinterpret_cast<const float4*>(&sW1[k * 64 + cg * 4]);
        acc[0][0] += a0 * bb.x; acc[0][1] += a0 * bb.y; acc[0][2] += a0 * bb.z; acc[0][3] += a0 * bb.w;
        acc[1][0] += a1 * bb.x; acc[1][1] += a1 * bb.y; acc[1][2] += a1 * bb.z; acc[1][3] += a1 * bb.w;
    }
    float4 bv1 = *reinterpret_cast<const float4*>(&b1[cg * 4]);
    __syncthreads();
    #pragma unroll
    for (int i = 0; i < 2; ++i) {
        sP[(rg * 2 + i) * 129 + cg * 4 + 0] = elu_f(acc[i][0] + bv1.x);
        sP[(rg * 2 + i) * 129 + cg * 4 + 1] = elu_f(acc[i][1] + bv1.y);
        sP[(rg * 2 + i) * 129 + cg * 4 + 2] = elu_f(acc[i][2] + bv1.z);
        sP[(rg * 2 + i) * 129 + cg * 4 + 3] = elu_f(acc[i][3] + bv1.w);
    }
    __syncthreads();

    float acc2[2][4] = {};
    #pragma unroll 4
    for (int k = 0; k < 64; ++k) {
        float a0 = sP[(rg * 2 + 0) * 129 + k];
        float a1 = sP[(rg * 2 + 1) * 129 + k];
        float4 bb = *reinterpret_cast<const float4*>(&W2[k * 64 + cg * 4]);
        acc2[0][0] += a0 * bb.x; acc2[0][1] += a0 * bb.y; acc2[0][2] += a0 * bb.z; acc2[0][3] += a0 * bb.w;
        acc2[1][0] += a1 * bb.x; acc2[1][1] += a1 * bb.y; acc2[1][2] += a1 * bb.z; acc2[1][3] += a1 * bb.w;
    }
    float4 bv2 = *reinterpret_cast<const float4*>(&b2[cg * 4]);
    #pragma unroll
    for (int i = 0; i < 2; ++i) {
        float4 o = make_float4(acc2[i][0] + bv2.x, acc2[i][1] + bv2.y,
                               acc2[i][2] + bv2.z, acc2[i][3] + bv2.w);
        *reinterpret_cast<float4*>(&hout[(r0 + rg * 2 + i) * 64 + cg * 4]) = o;
    }
}

// ---------------- partial[yb,xb,:] = per-block head GEMV partial ----------------
// R5: 8-deep inline-asm rolling load pipeline; steady-state wait is vmcnt(7),
// never 0. sched_barrier(0) after each wait pins uses below the wait (rule:
// reg-only FMAs otherwise hoist across asm waits despite "memory" clobber).
__global__ __launch_bounds__(256) void k_head(const float* __restrict__ phi,   // [8][ND]
                                              const float* __restrict__ w0a,
                                              const float* __restrict__ w1a,
                                              float* __restrict__ part) {      // [2][XB][1024]
    __shared__ float smem[4 * 32 * 33];    // 16.9 KB; phi chunk (8*KC=2560 fl) shares it
    const float* wa = blockIdx.y ? w1a : w0a;
    int t = threadIdx.x;
    int k0 = blockIdx.x * KC;

    #pragma unroll
    for (int b = 0; b < 8; ++b)
        for (int kk = t; kk < KC; kk += 256)
            smem[b * KC + kk] = phi[(long)b * ND + k0 + kk];
    __syncthreads();

    int w = t >> 6, l = t & 63;
    int h4 = l & 31, kh = l >> 5;
    int kl = w * 2 + kh;                       // [0,8)
    const float* wp = wa + (long)(k0 + kl) * H + h4 * 4;

    float4 acc[8];
    #pragma unroll
    for (int b = 0; b < 8; ++b) acc[b] = make_float4(0.f, 0.f, 0.f, 0.f);

    // ---- 8-deep rolling pipeline over the NIT=40 weight loads ----
    f32x4 buf[8];
    const float* wq = wp;                      // issue pointer
    #pragma unroll
    for (int j = 0; j < 8; ++j) {              // prologue: issue loads 0..7
        asm volatile("global_load_dwordx4 %0, %1, off"
                     : "=v"(buf[j]) : "v"(wq));
        wq += 8 * H;
    }

#define CONSUME(I)                                                         \
    {                                                                      \
        f32x4 w4 = buf[(I) & 7];                                           \
        int kk = (I) * 8 + kl;                                             \
        _Pragma("unroll")                                                  \
        for (int b = 0; b < 8; ++b) {                                      \
            float p = smem[b * KC + kk];                                   \
            acc[b].x += p * w4.x; acc[b].y += p * w4.y;                    \
            acc[b].z += p * w4.z; acc[b].w += p * w4.w;                    \
        }                                                                  \
    }

    #pragma unroll
    for (int i = 0; i < NIT - 8; ++i) {        // steady state: i = 0..31
        asm volatile("s_waitcnt vmcnt(7)" ::: "memory");
        __builtin_amdgcn_sched_barrier(0);
        CONSUME(i);
        asm volatile("global_load_dwordx4 %0, %1, off"
                     : "=v"(buf[i & 7]) : "v"(wq));
        wq += 8 * H;
    }

#define EPI(I, CNT)                                                        \
    {                                                                      \
        asm volatile("s_waitcnt vmcnt(" #CNT ")" ::: "memory");            \
        __builtin_amdgcn_sched_barrier(0);                                 \
        CONSUME(I);                                                        \
    }
    EPI(32, 7) EPI(33, 6) EPI(34, 5) EPI(35, 4)
    EPI(36, 3) EPI(37, 2) EPI(38, 1) EPI(39, 0)
#undef EPI
#undef CONSUME

    // merge the two kh half-waves in-register
    #pragma unroll
    for (int b = 0; b < 8; ++b) {
        acc[b].x += __shfl_xor(acc[b].x, 32);
        acc[b].y += __shfl_xor(acc[b].y, 32);
        acc[b].z += __shfl_xor(acc[b].z, 32);
        acc[b].w += __shfl_xor(acc[b].w, 32);
    }
    __syncthreads();   // phi reads done; smem reused for partials
    if (kh == 0) {
        int base = (w * 32 + h4) * 33;
        #pragma unroll
        for (int b = 0; b < 8; ++b) {
            smem[base + b * 4 + 0] = acc[b].x;
            smem[base + b * 4 + 1] = acc[b].y;
            smem[base + b * 4 + 2] = acc[b].z;
            smem[base + b * 4 + 3] = acc[b].w;
        }
    }
    __syncthreads();

    int h4r = t & 31, br = t >> 5;
    float s0 = 0.f, s1 = 0.f, s2 = 0.f, s3 = 0.f;
    #pragma unroll
    for (int wv = 0; wv < 4; ++wv) {
        int idx = (wv * 32 + h4r) * 33 + br * 4;
        s0 += smem[idx + 0]; s1 += smem[idx + 1];
        s2 += smem[idx + 2]; s3 += smem[idx + 3];
    }
    float* pb = part + ((long)blockIdx.y * XB + blockIdx.x) * 1024;
    *reinterpret_cast<float4*>(&pb[br * H + h4r * 4]) =
        make_float4(s0, s1, s2, s3);
}

// ---------------- hidden[y*1024+j] = sum_x part[y,x,j] ----------------
// grid (8, 16): 2048 outputs x 16 x-chunks; coalesced column sums; 32K spread atomics.
__global__ __launch_bounds__(256) void k_reduce(const float* __restrict__ part,
                                                float* __restrict__ hidden) {
    int idx = blockIdx.x * 256 + threadIdx.x;      // [0, 2048)
    int c = blockIdx.y;                            // [0, 16)
    int y = idx >> 10, j = idx & 1023;
    const float* p = part + (long)y * XB * 1024 + j;
    int x0 = (XB * c) >> 4, x1 = (XB * (c + 1)) >> 4;
    float s0 = 0.f, s1 = 0.f, s2 = 0.f, s3 = 0.f;
    int x = x0;
    for (; x + 3 < x1; x += 4) {
        s0 += p[(long)(x + 0) * 1024];
        s1 += p[(long)(x + 1) * 1024];
        s2 += p[(long)(x + 2) * 1024];
        s3 += p[(long)(x + 3) * 1024];
    }
    for (; x < x1; ++x) s0 += p[(long)x * 1024];
    unsafeAtomicAdd(&hidden[y * 1024 + j], s0 + s1 + s2 + s3);
}

// ---------------- out[b, head*2+j] = elu(hidden+ba) @ wb + bb ----------------
__global__ __launch_bounds__(64) void k_final(const float* __restrict__ hidden,
                                              const float* __restrict__ b0a,
                                              const float* __restrict__ w0b,
                                              const float* __restrict__ b0b,
                                              const float* __restrict__ b1a,
                                              const float* __restrict__ w1b,
                                              const float* __restrict__ b1b,
                                              float* __restrict__ out) {
    int t = threadIdx.x;
    if (t >= 32) return;
    int head = t >> 4, b = (t >> 1) & 7, j = t & 1;
    const float* hid = hidden + head * (8 * H) + b * H;
    const float* ba = head ? b1a : b0a;
    const float* wb = head ? w1b : w0b;
    const float* bb = head ? b1b : b0b;
    float acc = 0.0f;
    for (int hh = 0; hh < H; ++hh)
        acc += elu_f(hid[hh] + ba[hh]) * wb[hh * 2 + j];
    out[b * 4 + head * 2 + j] = acc + bb[j];
}

extern "C" void kernel_launch(void* const* d_in, const int* in_sizes, int n_in,
                              void* d_out, int out_size, void* d_ws, size_t ws_size,
                              hipStream_t stream) {
    const float* x      = (const float*)d_in[0];
    const int*   edges  = (const int*)d_in[1];
    const float* emb    = (const float*)d_in[2];
    const float* c1_pw1 = (const float*)d_in[3];
    const float* c1_pw2 = (const float*)d_in[4];
    const float* c1_uw1 = (const float*)d_in[5];
    const float* c1_ub1 = (const float*)d_in[6];
    const float* c1_uw2 = (const float*)d_in[7];
    const float* c1_ub2 = (const float*)d_in[8];
    const float* c2_pw1 = (const float*)d_in[9];
    const float* c2_pw2 = (const float*)d_in[10];
    const float* c2_uw1 = (const float*)d_in[11];
    const float* c2_ub1 = (const float*)d_in[12];
    const float* c2_uw2 = (const float*)d_in[13];
    const float* c2_ub2 = (const float*)d_in[14];
    const float* w0a    = (const float*)d_in[15];
    const float* b0a    = (const float*)d_in[16];
    const float* w0b    = (const float*)d_in[17];
    const float* b0b    = (const float*)d_in[18];
    const float* w1a    = (const float*)d_in[19];
    const float* b1a    = (const float*)d_in[20];
    const float* w1b    = (const float*)d_in[21];
    const float* b1b    = (const float*)d_in[22];
    float* out = (float*)d_out;

    float* hA     = (float*)d_ws;          // [BN, D]
    float* hB     = hA + BND;
    float* Mu     = hB + BND;              // also aliased as `part` for k_head
    float* agg    = Mu + BND;
    float* hidden = agg + BND;             // [2][8][H] = 2048 floats
    int* cnt      = (int*)(hidden + 2048); // [N]
    int* cursor   = cnt + N;               // [N]
    int* offs     = cursor + N;            // [N+1]
    int* elist    = offs + N + 1;          // [E]
    float* part   = Mu;                    // [2][XB][1024] = 2.048M floats <= BND

    hipMemsetAsync(hidden, 0, (2048 + 2 * N) * sizeof(float), stream);

    k_count<<<(E + 255) / 256, 256, 0, stream>>>(edges, cnt);
    k_scan<<<1, 256, 0, stream>>>(cnt, offs);
    k_fill<<<(E + 255) / 256, 256, 0, stream>>>(edges, offs, cursor, elist);

    // conv1 (prepare also materializes hA = x*emb)
    k_prepare<<<(BN + 127) / 128, 512, 0, stream>>>(x, emb, nullptr, c1_pw1, c1_pw2, Mu, hA);
    k_aggregate<<<BN / 4, 256, 0, stream>>>(Mu, offs, elist, agg);
    k_update<<<BN / 64, 512, 0, stream>>>(hA, agg, c1_uw1, c1_ub1, c1_uw2, c1_ub2, hB);

    // conv2
    k_prepare<<<(BN + 127) / 128, 512, 0, stream>>>(nullptr, emb, hB, c2_pw1, c2_pw2, Mu, nullptr);
    k_aggregate<<<BN / 4, 256, 0, stream>>>(Mu, offs, elist, agg);
    k_update<<<BN / 64, 512, 0, stream>>>(hB, agg, c2_uw1, c2_ub1, c2_uw2, c2_ub2, hA);

    // heads: partials (Mu is dead scratch by now) -> reduce -> final
    k_head<<<dim3(XB, 2), 256, 0, stream>>>(hA, w0a, w1a, part);
    k_reduce<<<dim3(8, 16), 256, 0, stream>>>(part, hidden);
    k_final<<<1, 64, 0, stream>>>(hidden, b0a, w0b, b0b, b1a, w1b, b1b, out);
}

// Round 2
// 611.621 us; speedup vs baseline: 1.0086x; 1.0048x over previous
//
#include <hip/hip_runtime.h>

// GNN TARnet: h = x*emb -> 2x graph conv -> two prob heads.
// R6: k_head weight streaming moved off the VGPR-return path onto
//     global_load_lds (direct-to-LDS DMA), 8-slot LDS ring, counted
//     vmcnt(7), no barriers in the hot loop (each thread reads back only
//     the 16B it staged). Theory: R5 proved per-wave outstanding depth is
//     not the lever (44->108 VGPR, same 2.9 TB/s) -> cap is the CU's
//     vector-return/miss-tracking path; the LDS-DMA path sidesteps it.
//     Everything except k_head identical to R5.

constexpr int B = 8, N = 5000, E = 160000, D = 64, H = 128;
constexpr int BN = B * N;           // 40000
constexpr int ND = N * D;           // 320000
constexpr long BND = (long)BN * D;  // 2,560,000
constexpr int KC = 320;             // k-chunk per head block
constexpr int NIT = KC / 8;         // 40 k-iters per thread
constexpr int XB = ND / KC;         // 1000 x-blocks per head

using f32x4 = __attribute__((ext_vector_type(4))) float;

__device__ __forceinline__ float elu_f(float x) {
    return x > 0.0f ? x : __expf(x) - 1.0f;
}

__device__ __forceinline__ void g2lds16(const float* g, float* l) {
    __builtin_amdgcn_global_load_lds(
        (const __attribute__((address_space(1))) void*)g,
        (__attribute__((address_space(3))) void*)l, 16, 0, 0);
}

// ---------------- CSR build (edges grouped by child) ----------------
__global__ __launch_bounds__(256) void k_count(const int* __restrict__ edges,
                                               int* __restrict__ cnt) {
    int i = blockIdx.x * 256 + threadIdx.x;
    if (i < E) atomicAdd(&cnt[edges[2 * i + 1]], 1);
}

__global__ __launch_bounds__(256) void k_scan(const int* __restrict__ cnt,
                                              int* __restrict__ offs) {
    __shared__ int part[256];
    int t = threadIdx.x;
    const int CH = 20;
    int base = t * CH;
    int s = 0;
    for (int i = 0; i < CH; ++i) { int idx = base + i; if (idx < N) s += cnt[idx]; }
    part[t] = s;
    __syncthreads();
    for (int off = 1; off < 256; off <<= 1) {
        int add = (t >= off) ? part[t - off] : 0;
        __syncthreads();
        part[t] += add;
        __syncthreads();
    }
    int run = part[t] - s;
    for (int i = 0; i < CH; ++i) {
        int idx = base + i;
        if (idx < N) { offs[idx] = run; run += cnt[idx]; }
    }
    if (t == 255) offs[N] = run;
}

__global__ __launch_bounds__(256) void k_fill(const int* __restrict__ edges,
                                              const int* __restrict__ offs,
                                              int* __restrict__ cursor,
                                              int* __restrict__ elist) {
    int i = blockIdx.x * 256 + threadIdx.x;
    if (i < E) {
        int child = edges[2 * i + 1];
        int pos = offs[child] + atomicAdd(&cursor[child], 1);
        elist[pos] = edges[2 * i];
    }
}

// ---------------- prepare: M = elu(elu(h @ W1) @ W2) ----------------
__global__ __launch_bounds__(512) void k_prepare(const float* __restrict__ xsrc,
                                                 const float* __restrict__ emb,
                                                 const float* __restrict__ hin,
                                                 const float* __restrict__ W1,
                                                 const float* __restrict__ W2,
                                                 float* __restrict__ M,
                                                 float* __restrict__ hwt) {
    __shared__ float sW1[64 * 64];      // 16 KB
    __shared__ float sP[128 * 65];      // 33.3 KB
    int t = threadIdx.x;
    int r0 = blockIdx.x * 128;
    for (int i = t; i < 4096; i += 512) sW1[i] = W1[i];
    if (xsrc) {
        for (int i = t; i < 128 * 64; i += 512) {
            int r = i >> 6, c = i & 63;
            int row = r0 + r;
            float v = 0.0f;
            if (row < BN) {
                int n = row % N;
                v = xsrc[row] * emb[n * 64 + c];
                hwt[(long)row * 64 + c] = v;
            }
            sP[r * 65 + c] = v;
        }
    } else {
        for (int i = t; i < 128 * 64; i += 512) {
            int r = i >> 6, c = i & 63;
            int row = r0 + r;
            sP[r * 65 + c] = (row < BN) ? hin[(long)row * 64 + c] : 0.0f;
        }
    }
    __syncthreads();

    int cg = t & 15, rg = t >> 4;
    float acc[4][4] = {};
    #pragma unroll 4
    for (int k = 0; k < 64; ++k) {
        float a[4];
        #pragma unroll
        for (int i = 0; i < 4; ++i) a[i] = sP[(rg * 4 + i) * 65 + k];
        float4 bb = *reinterpret_cast<const float4*>(&sW1[k * 64 + cg * 4]);
        #pragma unroll
        for (int i = 0; i < 4; ++i) {
            acc[i][0] += a[i] * bb.x; acc[i][1] += a[i] * bb.y;
            acc[i][2] += a[i] * bb.z; acc[i][3] += a[i] * bb.w;
        }
    }
    __syncthreads();
    #pragma unroll
    for (int i = 0; i < 4; ++i)
        #pragma unroll
        for (int j = 0; j < 4; ++j)
            sP[(rg * 4 + i) * 65 + cg * 4 + j] = elu_f(acc[i][j]);
    __syncthreads();

    float acc2[4][4] = {};
    #pragma unroll 4
    for (int k = 0; k < 64; ++k) {
        float a[4];
        #pragma unroll
        for (int i = 0; i < 4; ++i) a[i] = sP[(rg * 4 + i) * 65 + k];
        float4 bb = *reinterpret_cast<const float4*>(&W2[k * 64 + cg * 4]);
        #pragma unroll
        for (int i = 0; i < 4; ++i) {
            acc2[i][0] += a[i] * bb.x; acc2[i][1] += a[i] * bb.y;
            acc2[i][2] += a[i] * bb.z; acc2[i][3] += a[i] * bb.w;
        }
    }
    #pragma unroll
    for (int i = 0; i < 4; ++i) {
        int row = r0 + rg * 4 + i;
        if (row < BN) {
            float4 o = make_float4(elu_f(acc2[i][0]), elu_f(acc2[i][1]),
                                   elu_f(acc2[i][2]), elu_f(acc2[i][3]));
            *reinterpret_cast<float4*>(&M[(long)row * 64 + cg * 4]) = o;
        }
    }
}

// ---------------- agg[b,n,:] = sum_{e: child==n} M[b, parent_e, :] ----------------
__global__ __launch_bounds__(256) void k_aggregate(const float* __restrict__ M,
                                                   const int* __restrict__ offs,
                                                   const int* __restrict__ elist,
                                                   float* __restrict__ agg) {
    int t = threadIdx.x;
    int lane = t & 63, wv = t >> 6;
    int bn = blockIdx.x * 4 + wv;
    int b = bn / N;
    int n = bn - b * N;
    int e0 = offs[n], e1 = offs[n + 1];
    const float* Mb = M + (long)b * ND;
    int h4 = lane & 15, le = lane >> 4;
    float4 acc = make_float4(0.f, 0.f, 0.f, 0.f);
    for (int e = e0 + le; e < e1; e += 4) {
        int p = elist[e];
        float4 v = *reinterpret_cast<const float4*>(&Mb[(long)p * 64 + h4 * 4]);
        acc.x += v.x; acc.y += v.y; acc.z += v.z; acc.w += v.w;
    }
    #pragma unroll
    for (int m = 16; m <= 32; m <<= 1) {
        acc.x += __shfl_xor(acc.x, m);
        acc.y += __shfl_xor(acc.y, m);
        acc.z += __shfl_xor(acc.z, m);
        acc.w += __shfl_xor(acc.w, m);
    }
    if (le == 0)
        *reinterpret_cast<float4*>(&agg[(long)bn * 64 + h4 * 4]) = acc;
}

// ---------------- fused update: hout = (elu([h,agg]@W1 + b1)) @ W2 + b2 ----------------
__global__ __launch_bounds__(512) void k_update(const float* __restrict__ h,
                                                const float* __restrict__ agg,
                                                const float* __restrict__ W1,   // [128][64]
                                                const float* __restrict__ b1,
                                                const float* __restrict__ W2,   // [64][64]
                                                const float* __restrict__ b2,
                                                float* __restrict__ hout) {
    __shared__ float sW1[128 * 64];     // 32 KB
    __shared__ float sP[64 * 129];      // 33 KB
    int t = threadIdx.x;
    long r0 = (long)blockIdx.x * 64;
    for (int i = t; i < 128 * 64; i += 512) sW1[i] = W1[i];
    for (int i = t; i < 64 * 128; i += 512) {
        int r = i >> 7, k = i & 127;
        long row = r0 + r;
        float v = (k < 64) ? h[row * 64 + k] : agg[row * 64 + (k - 64)];
        sP[r * 129 + k] = v;
    }
    __syncthreads();

    int cg = t & 15, rg = t >> 4;
    float acc[2][4] = {};
    #pragma unroll 4
    for (int k = 0; k < 128; ++k) {
        float a0 = sP[(rg * 2 + 0) * 129 + k];
        float a1 = sP[(rg * 2 + 1) * 129 + k];
        float4 bb = *reinterpret_cast<const float4*>(&sW1[k * 64 + cg * 4]);
        acc[0][0] += a0 * bb.x; acc[0][1] += a0 * bb.y; acc[0][2] += a0 * bb.z; acc[0][3] += a0 * bb.w;
        acc[1][0] += a1 * bb.x; acc[1][1] += a1 * bb.y; acc[1][2] += a1 * bb.z; acc[1][3] += a1 * bb.w;
    }
    float4 bv1 = *reinterpret_cast<const float4*>(&b1[cg * 4]);
    __syncthreads();
    #pragma unroll
    for (int i = 0; i < 2; ++i) {
        sP[(rg * 2 + i) * 129 + cg * 4 + 0] = elu_f(acc[i][0] + bv1.x);
        sP[(rg * 2 + i) * 129 + cg * 4 + 1] = elu_f(acc[i][1] + bv1.y);
        sP[(rg * 2 + i) * 129 + cg * 4 + 2] = elu_f(acc[i][2] + bv1.z);
        sP[(rg * 2 + i) * 129 + cg * 4 + 3] = elu_f(acc[i][3] + bv1.w);
    }
    __syncthreads();

    float acc2[2][4] = {};
    #pragma unroll 4
    for (int k = 0; k < 64; ++k) {
        float a0 = sP[(rg * 2 + 0) * 129 + k];
        float a1 = sP[(rg * 2 + 1) * 129 + k];
        float4 bb = *reinterpret_cast<const float4*>(&W2[k * 64 + cg * 4]);
        acc2[0][0] += a0 * bb.x; acc2[0][1] += a0 * bb.y; acc2[0][2] += a0 * bb.z; acc2[0][3] += a0 * bb.w;
        acc2[1][0] += a1 * bb.x; acc2[1][1] += a1 * bb.y; acc2[1][2] += a1 * bb.z; acc2[1][3] += a1 * bb.w;
    }
    float4 bv2 = *reinterpret_cast<const float4*>(&b2[cg * 4]);
    #pragma unroll
    for (int i = 0; i < 2; ++i) {
        float4 o = make_float4(acc2[i][0] + bv2.x, acc2[i][1] + bv2.y,
                               acc2[i][2] + bv2.z, acc2[i][3] + bv2.w);
        *reinterpret_cast<float4*>(&hout[(r0 + rg * 2 + i) * 64 + cg * 4]) = o;
    }
}

// ---------------- partial[yb,xb,:] = per-block head GEMV partial ----------------
// R6: weights stream through an 8-slot LDS ring via global_load_lds DMA.
// Each thread reads back exactly the 16B it staged -> no barriers in loop.
// vmcnt accounting: entering STEP(i) (steady) outstanding = 8, oldest carries
// iter i's data -> wait vmcnt(7). Epilogue drains 7..0. lgkmcnt(0)+
// sched_barrier(0) before FMAs (rule #18); slot reissue after the fence so
// the ds_read has retired before the DMA overwrite issues.
__global__ __launch_bounds__(256) void k_head(const float* __restrict__ phi,   // [8][ND]
                                              const float* __restrict__ w0a,
                                              const float* __restrict__ w1a,
                                              float* __restrict__ part) {      // [2][XB][1024]
    __shared__ float smem[4 * 32 * 33];              // 16.9 KB; phi chunk + partials
    __shared__ __align__(16) float wb[8][1024];      // 32 KB ring (8 x 4KB)
    const float* wa = blockIdx.y ? w1a : w0a;
    int t = threadIdx.x;
    int k0 = blockIdx.x * KC;

    #pragma unroll
    for (int b = 0; b < 8; ++b)
        for (int kk = t; kk < KC; kk += 256)
            smem[b * KC + kk] = phi[(long)b * ND + k0 + kk];
    __syncthreads();

    int w = t >> 6, l = t & 63;
    int h4 = l & 31, kh = l >> 5;
    int kl = w * 2 + kh;                       // [0,8)
    const float* wp = wa + (long)(k0 + kl) * H + h4 * 4;

    float4 acc[8];
    #pragma unroll
    for (int b = 0; b < 8; ++b) acc[b] = make_float4(0.f, 0.f, 0.f, 0.f);

    // per-thread LDS byte offset of its own 16B within slot 0
    unsigned my_off =
        (unsigned)(size_t)(__attribute__((address_space(3))) float*)&wb[0][0]
        + (unsigned)t * 16u;

    // prologue: issue DMAs for iters 0..7 (after the barrier -> no drain)
    const float* wq = wp;
    #pragma unroll
    for (int j = 0; j < 8; ++j) {
        g2lds16(wq, &wb[j][w * 256]);
        wq += 8 * H;
    }

#define STEP(I, CNT, OFF, RE)                                              \
    {                                                                      \
        asm volatile("s_waitcnt vmcnt(" #CNT ")" ::: "memory");            \
        __builtin_amdgcn_sched_barrier(0);                                 \
        f32x4 w4;                                                          \
        asm volatile("ds_read_b128 %0, %1 offset:" #OFF                    \
                     : "=v"(w4) : "v"(my_off));                            \
        float pv[8];                                                       \
        _Pragma("unroll")                                                  \
        for (int b = 0; b < 8; ++b)                                        \
            pv[b] = smem[b * KC + (I) * 8 + kl];                           \
        asm volatile("s_waitcnt lgkmcnt(0)" ::: "memory");                 \
        __builtin_amdgcn_sched_barrier(0);                                 \
        _Pragma("unroll")                                                  \
        for (int b = 0; b < 8; ++b) {                                      \
            acc[b].x += pv[b] * w4.x; acc[b].y += pv[b] * w4.y;            \
            acc[b].z += pv[b] * w4.z; acc[b].w += pv[b] * w4.w;            \
        }                                                                  \
        if (RE) {                                                          \
            g2lds16(wq, &wb[(I) & 7][w * 256]);                            \
            wq += 8 * H;                                                   \
        }                                                                  \
    }

#define ROUND8(BASE, RE)                                                   \
    STEP(BASE + 0, 7, 0,     RE) STEP(BASE + 1, 7, 4096,  RE)              \
    STEP(BASE + 2, 7, 8192,  RE) STEP(BASE + 3, 7, 12288, RE)              \
    STEP(BASE + 4, 7, 16384, RE) STEP(BASE + 5, 7, 20480, RE)              \
    STEP(BASE + 6, 7, 24576, RE) STEP(BASE + 7, 7, 28672, RE)

    ROUND8(0, 1) ROUND8(8, 1) ROUND8(16, 1) ROUND8(24, 1)
    // epilogue: iters 32..39, no reissue, drain 7..0
    STEP(32, 7, 0,     0) STEP(33, 6, 4096,  0)
    STEP(34, 5, 8192,  0) STEP(35, 4, 12288, 0)
    STEP(36, 3, 16384, 0) STEP(37, 2, 20480, 0)
    STEP(38, 1, 24576, 0) STEP(39, 0, 28672, 0)
#undef ROUND8
#undef STEP

    // merge the two kh half-waves in-register
    #pragma unroll
    for (int b = 0; b < 8; ++b) {
        acc[b].x += __shfl_xor(acc[b].x, 32);
        acc[b].y += __shfl_xor(acc[b].y, 32);
        acc[b].z += __shfl_xor(acc[b].z, 32);
        acc[b].w += __shfl_xor(acc[b].w, 32);
    }
    __syncthreads();   // phi reads done; smem reused for partials
    if (kh == 0) {
        int base = (w * 32 + h4) * 33;
        #pragma unroll
        for (int b = 0; b < 8; ++b) {
            smem[base + b * 4 + 0] = acc[b].x;
            smem[base + b * 4 + 1] = acc[b].y;
            smem[base + b * 4 + 2] = acc[b].z;
            smem[base + b * 4 + 3] = acc[b].w;
        }
    }
    __syncthreads();

    int h4r = t & 31, br = t >> 5;
    float s0 = 0.f, s1 = 0.f, s2 = 0.f, s3 = 0.f;
    #pragma unroll
    for (int wv = 0; wv < 4; ++wv) {
        int idx = (wv * 32 + h4r) * 33 + br * 4;
        s0 += smem[idx + 0]; s1 += smem[idx + 1];
        s2 += smem[idx + 2]; s3 += smem[idx + 3];
    }
    float* pb = part + ((long)blockIdx.y * XB + blockIdx.x) * 1024;
    *reinterpret_cast<float4*>(&pb[br * H + h4r * 4]) =
        make_float4(s0, s1, s2, s3);
}

// ---------------- hidden[y*1024+j] = sum_x part[y,x,j] ----------------
// grid (8, 16): 2048 outputs x 16 x-chunks; coalesced column sums; 32K spread atomics.
__global__ __launch_bounds__(256) void k_reduce(const float* __restrict__ part,
                                                float* __restrict__ hidden) {
    int idx = blockIdx.x * 256 + threadIdx.x;      // [0, 2048)
    int c = blockIdx.y;                            // [0, 16)
    int y = idx >> 10, j = idx & 1023;
    const float* p = part + (long)y * XB * 1024 + j;
    int x0 = (XB * c) >> 4, x1 = (XB * (c + 1)) >> 4;
    float s0 = 0.f, s1 = 0.f, s2 = 0.f, s3 = 0.f;
    int x = x0;
    for (; x + 3 < x1; x += 4) {
        s0 += p[(long)(x + 0) * 1024];
        s1 += p[(long)(x + 1) * 1024];
        s2 += p[(long)(x + 2) * 1024];
        s3 += p[(long)(x + 3) * 1024];
    }
    for (; x < x1; ++x) s0 += p[(long)x * 1024];
    unsafeAtomicAdd(&hidden[y * 1024 + j], s0 + s1 + s2 + s3);
}

// ---------------- out[b, head*2+j] = elu(hidden+ba) @ wb + bb ----------------
__global__ __launch_bounds__(64) void k_final(const float* __restrict__ hidden,
                                              const float* __restrict__ b0a,
                                              const float* __restrict__ w0b,
                                              const float* __restrict__ b0b,
                                              const float* __restrict__ b1a,
                                              const float* __restrict__ w1b,
                                              const float* __restrict__ b1b,
                                              float* __restrict__ out) {
    int t = threadIdx.x;
    if (t >= 32) return;
    int head = t >> 4, b = (t >> 1) & 7, j = t & 1;
    const float* hid = hidden + head * (8 * H) + b * H;
    const float* ba = head ? b1a : b0a;
    const float* wb = head ? w1b : w0b;
    const float* bb = head ? b1b : b0b;
    float acc = 0.0f;
    for (int hh = 0; hh < H; ++hh)
        acc += elu_f(hid[hh] + ba[hh]) * wb[hh * 2 + j];
    out[b * 4 + head * 2 + j] = acc + bb[j];
}

extern "C" void kernel_launch(void* const* d_in, const int* in_sizes, int n_in,
                              void* d_out, int out_size, void* d_ws, size_t ws_size,
                              hipStream_t stream) {
    const float* x      = (const float*)d_in[0];
    const int*   edges  = (const int*)d_in[1];
    const float* emb    = (const float*)d_in[2];
    const float* c1_pw1 = (const float*)d_in[3];
    const float* c1_pw2 = (const float*)d_in[4];
    const float* c1_uw1 = (const float*)d_in[5];
    const float* c1_ub1 = (const float*)d_in[6];
    const float* c1_uw2 = (const float*)d_in[7];
    const float* c1_ub2 = (const float*)d_in[8];
    const float* c2_pw1 = (const float*)d_in[9];
    const float* c2_pw2 = (const float*)d_in[10];
    const float* c2_uw1 = (const float*)d_in[11];
    const float* c2_ub1 = (const float*)d_in[12];
    const float* c2_uw2 = (const float*)d_in[13];
    const float* c2_ub2 = (const float*)d_in[14];
    const float* w0a    = (const float*)d_in[15];
    const float* b0a    = (const float*)d_in[16];
    const float* w0b    = (const float*)d_in[17];
    const float* b0b    = (const float*)d_in[18];
    const float* w1a    = (const float*)d_in[19];
    const float* b1a    = (const float*)d_in[20];
    const float* w1b    = (const float*)d_in[21];
    const float* b1b    = (const float*)d_in[22];
    float* out = (float*)d_out;

    float* hA     = (float*)d_ws;          // [BN, D]
    float* hB     = hA + BND;
    float* Mu     = hB + BND;              // also aliased as `part` for k_head
    float* agg    = Mu + BND;
    float* hidden = agg + BND;             // [2][8][H] = 2048 floats
    int* cnt      = (int*)(hidden + 2048); // [N]
    int* cursor   = cnt + N;               // [N]
    int* offs     = cursor + N;            // [N+1]
    int* elist    = offs + N + 1;          // [E]
    float* part   = Mu;                    // [2][XB][1024] = 2.048M floats <= BND

    hipMemsetAsync(hidden, 0, (2048 + 2 * N) * sizeof(float), stream);

    k_count<<<(E + 255) / 256, 256, 0, stream>>>(edges, cnt);
    k_scan<<<1, 256, 0, stream>>>(cnt, offs);
    k_fill<<<(E + 255) / 256, 256, 0, stream>>>(edges, offs, cursor, elist);

    // conv1 (prepare also materializes hA = x*emb)
    k_prepare<<<(BN + 127) / 128, 512, 0, stream>>>(x, emb, nullptr, c1_pw1, c1_pw2, Mu, hA);
    k_aggregate<<<BN / 4, 256, 0, stream>>>(Mu, offs, elist, agg);
    k_update<<<BN / 64, 512, 0, stream>>>(hA, agg, c1_uw1, c1_ub1, c1_uw2, c1_ub2, hB);

    // conv2
    k_prepare<<<(BN + 127) / 128, 512, 0, stream>>>(nullptr, emb, hB, c2_pw1, c2_pw2, Mu, nullptr);
    k_aggregate<<<BN / 4, 256, 0, stream>>>(Mu, offs, elist, agg);
    k_update<<<BN / 64, 512, 0, stream>>>(hB, agg, c2_uw1, c2_ub1, c2_uw2, c2_ub2, hA);

    // heads: partials (Mu is dead scratch by now) -> reduce -> final
    k_head<<<dim3(XB, 2), 256, 0, stream>>>(hA, w0a, w1a, part);
    k_reduce<<<dim3(8, 16), 256, 0, stream>>>(part, hidden);
    k_final<<<1, 64, 0, stream>>>(hidden, b0a, w0b, b0b, b1a, w1b, b1b, out);
}